// Round 1
// baseline (893.090 us; speedup 1.0000x reference)
//
#include <hip/hip_runtime.h>
#include <cstdint>
#include <cstddef>

#define DD 768
#define TSCALE 20.0f

__device__ inline float wsum(float v){
  #pragma unroll
  for (int m = 1; m < 64; m <<= 1) v += __shfl_xor(v, m, 64);
  return v;
}
__device__ inline float wmax(float v){
  #pragma unroll
  for (int m = 1; m < 64; m <<= 1) v = fmaxf(v, __shfl_xor(v, m, 64));
  return v;
}

// Normalize rows: obj (8*NB rows), arg slots {0,2,3} (3*NB rows), text slot 1 (NB rows)
__global__ __launch_bounds__(64) void norm_rows(
    const float* __restrict__ obj, const float* __restrict__ txt,
    float* __restrict__ objn, float* __restrict__ argn, float* __restrict__ t1n, int NB)
{
  int row = blockIdx.x, lane = threadIdx.x;
  int NO = NB * 8, NA = NB * 3;
  const float* src; float* dst;
  if (row < NO) {
    src = obj + (size_t)row * DD; dst = objn + (size_t)row * DD;
  } else if (row < NO + NA) {
    int r = row - NO; int i = r / 3, j = r - i * 3; int s = (j == 0) ? 0 : (j + 1);
    src = txt + ((size_t)i * 4 + s) * DD; dst = argn + (size_t)r * DD;
  } else {
    int i = row - NO - NA;
    src = txt + ((size_t)i * 4 + 1) * DD; dst = t1n + (size_t)i * DD;
  }
  float v[12]; float ss = 0.f;
  #pragma unroll
  for (int q = 0; q < 12; ++q){ v[q] = src[lane + q * 64]; ss += v[q] * v[q]; }
  ss = wsum(ss);
  float inv = 1.0f / fmaxf(sqrtf(ss), 1e-12f);
  #pragma unroll
  for (int q = 0; q < 12; ++q) dst[lane + q * 64] = v[q] * inv;
}

// Per (i,j) arg row: dots with its own 8 objects -> scaled max, argmax
__global__ __launch_bounds__(64) void diag_kernel(
    const float* __restrict__ argn, const float* __restrict__ objn,
    float* __restrict__ diagmax, int* __restrict__ diagidx)
{
  int r = blockIdx.x, lane = threadIdx.x;
  int i = r / 3;
  float a[12];
  #pragma unroll
  for (int q = 0; q < 12; ++q) a[q] = argn[(size_t)r * DD + lane + q * 64];
  float best = -3.0e38f; int bi = 0;
  for (int k = 0; k < 8; ++k){
    const float* o = objn + (size_t)(i * 8 + k) * DD;
    float s = 0.f;
    #pragma unroll
    for (int q = 0; q < 12; ++q) s += a[q] * o[lane + q * 64];
    s = wsum(s);
    if (s > best){ best = s; bi = k; }   // strict > keeps first index on tie (jnp.argmax)
  }
  if (lane == 0){ diagmax[r] = best * TSCALE; diagidx[r] = bi; }
}

// Big GEMM: logits = argn @ objn^T * 20, fused per-row sum(exp(logit-20)) via atomics.
// Tile 128x128, 256 threads, 8x8 per thread, BK=8.
__global__ __launch_bounds__(256) void wpg_gemm(
    const float* __restrict__ A, const float* __restrict__ Bm,
    float* __restrict__ sumexp)
{
  __shared__ float As[8][128], Bs[8][128];
  int tid = threadIdx.x;
  int tx = tid & 15, ty = tid >> 4;
  int bx = blockIdx.x, by = blockIdx.y;
  float acc[8][8] = {};
  int lrow = tid >> 1;            // 0..127
  int lkk  = (tid & 1) * 4;       // 0 or 4
  const float* pa = A  + ((size_t)(by * 128 + lrow)) * DD + lkk;
  const float* pb = Bm + ((size_t)(bx * 128 + lrow)) * DD + lkk;
  for (int k0 = 0; k0 < DD; k0 += 8){
    float4 av = *(const float4*)(pa + k0);
    float4 bv = *(const float4*)(pb + k0);
    __syncthreads();
    As[lkk + 0][lrow] = av.x; As[lkk + 1][lrow] = av.y; As[lkk + 2][lrow] = av.z; As[lkk + 3][lrow] = av.w;
    Bs[lkk + 0][lrow] = bv.x; Bs[lkk + 1][lrow] = bv.y; Bs[lkk + 2][lrow] = bv.z; Bs[lkk + 3][lrow] = bv.w;
    __syncthreads();
    #pragma unroll
    for (int kk = 0; kk < 8; ++kk){
      float4 a0 = *(const float4*)&As[kk][ty * 8];
      float4 a1 = *(const float4*)&As[kk][ty * 8 + 4];
      float4 b0 = *(const float4*)&Bs[kk][tx * 8];
      float4 b1 = *(const float4*)&Bs[kk][tx * 8 + 4];
      float ar[8] = {a0.x, a0.y, a0.z, a0.w, a1.x, a1.y, a1.z, a1.w};
      float br[8] = {b0.x, b0.y, b0.z, b0.w, b1.x, b1.y, b1.z, b1.w};
      #pragma unroll
      for (int i2 = 0; i2 < 8; ++i2)
        #pragma unroll
        for (int j = 0; j < 8; ++j) acc[i2][j] = fmaf(ar[i2], br[j], acc[i2][j]);
    }
  }
  // epilogue: row partial sums of exp(20*acc - 20)
  #pragma unroll
  for (int i2 = 0; i2 < 8; ++i2){
    float s = 0.f;
    #pragma unroll
    for (int j = 0; j < 8; ++j) s += expf(acc[i2][j] * TSCALE - TSCALE);
    #pragma unroll
    for (int m = 1; m < 16; m <<= 1) s += __shfl_xor(s, m, 64);
    if (tx == 0) atomicAdd(&sumexp[by * 128 + ty * 8 + i2], s);
  }
}

// te/ve assembly + normalize
__global__ __launch_bounds__(64) void teve_kernel(
    const float* __restrict__ argn, const float* __restrict__ objn, const float* __restrict__ t1n,
    const float* __restrict__ diagmax, const int* __restrict__ diagidx,
    float* __restrict__ ten, float* __restrict__ ven)
{
  int i = blockIdx.x, lane = threadIdx.x;
  float te[12], ve[12];
  #pragma unroll
  for (int q = 0; q < 12; ++q){ te[q] = t1n[(size_t)i * DD + lane + q * 64]; ve[q] = 0.f; }
  for (int j = 0; j < 3; ++j){
    int r = i * 3 + j;
    if (diagmax[r] > 1.0f){
      int k = diagidx[r];
      const float* ap = argn + (size_t)r * DD;
      const float* op = objn + (size_t)(i * 8 + k) * DD;
      #pragma unroll
      for (int q = 0; q < 12; ++q){ te[q] += ap[lane + q * 64]; ve[q] += op[lane + q * 64]; }
    }
  }
  float ss = 0.f;
  #pragma unroll
  for (int q = 0; q < 12; ++q) ss += te[q] * te[q];
  ss = wsum(ss);
  float inv = 1.0f / fmaxf(sqrtf(ss), 1e-12f);
  #pragma unroll
  for (int q = 0; q < 12; ++q) ten[(size_t)i * DD + lane + q * 64] = te[q] * inv;
  ss = 0.f;
  #pragma unroll
  for (int q = 0; q < 12; ++q) ss += ve[q] * ve[q];
  ss = wsum(ss);
  inv = 1.0f / fmaxf(sqrtf(ss), 1e-12f);   // ve==0 -> stays 0, matches x/max(||x||,eps)
  #pragma unroll
  for (int q = 0; q < 12; ++q) ven[(size_t)i * DD + lane + q * 64] = ve[q] * inv;
}

// EC GEMM: L = 20 * ten @ ven^T; fused row/col sum(exp(L-20)) + diag capture
__global__ __launch_bounds__(256) void ec_gemm(
    const float* __restrict__ A, const float* __restrict__ Bm,
    float* __restrict__ rowsum, float* __restrict__ colsum, float* __restrict__ Ldiag)
{
  __shared__ float As[8][128], Bs[8][128];
  __shared__ float csum[128];
  int tid = threadIdx.x;
  int tx = tid & 15, ty = tid >> 4;
  int bx = blockIdx.x, by = blockIdx.y;
  float acc[8][8] = {};
  int lrow = tid >> 1;
  int lkk  = (tid & 1) * 4;
  const float* pa = A  + ((size_t)(by * 128 + lrow)) * DD + lkk;
  const float* pb = Bm + ((size_t)(bx * 128 + lrow)) * DD + lkk;
  for (int k0 = 0; k0 < DD; k0 += 8){
    float4 av = *(const float4*)(pa + k0);
    float4 bv = *(const float4*)(pb + k0);
    __syncthreads();
    As[lkk + 0][lrow] = av.x; As[lkk + 1][lrow] = av.y; As[lkk + 2][lrow] = av.z; As[lkk + 3][lrow] = av.w;
    Bs[lkk + 0][lrow] = bv.x; Bs[lkk + 1][lrow] = bv.y; Bs[lkk + 2][lrow] = bv.z; Bs[lkk + 3][lrow] = bv.w;
    __syncthreads();
    #pragma unroll
    for (int kk = 0; kk < 8; ++kk){
      float4 a0 = *(const float4*)&As[kk][ty * 8];
      float4 a1 = *(const float4*)&As[kk][ty * 8 + 4];
      float4 b0 = *(const float4*)&Bs[kk][tx * 8];
      float4 b1 = *(const float4*)&Bs[kk][tx * 8 + 4];
      float ar[8] = {a0.x, a0.y, a0.z, a0.w, a1.x, a1.y, a1.z, a1.w};
      float br[8] = {b0.x, b0.y, b0.z, b0.w, b1.x, b1.y, b1.z, b1.w};
      #pragma unroll
      for (int i2 = 0; i2 < 8; ++i2)
        #pragma unroll
        for (int j = 0; j < 8; ++j) acc[i2][j] = fmaf(ar[i2], br[j], acc[i2][j]);
    }
  }
  if (tid < 128) csum[tid] = 0.f;
  __syncthreads();
  float ecol[8] = {};
  #pragma unroll
  for (int i2 = 0; i2 < 8; ++i2){
    float s = 0.f;
    #pragma unroll
    for (int j = 0; j < 8; ++j){
      float e = expf(acc[i2][j] * TSCALE - TSCALE);
      s += e; ecol[j] += e;
    }
    #pragma unroll
    for (int m = 1; m < 16; m <<= 1) s += __shfl_xor(s, m, 64);
    if (tx == 0) atomicAdd(&rowsum[by * 128 + ty * 8 + i2], s);
  }
  #pragma unroll
  for (int j = 0; j < 8; ++j) atomicAdd(&csum[tx * 8 + j], ecol[j]);
  __syncthreads();
  if (tid < 128) atomicAdd(&colsum[bx * 128 + tid], csum[tid]);
  if (bx == by && tx == ty){
    #pragma unroll
    for (int i2 = 0; i2 < 8; ++i2)
      Ldiag[by * 128 + ty * 8 + i2] = acc[i2][i2] * TSCALE;
  }
}

// Verb CE: one 64-thread block per row of [NB, C]
__global__ __launch_bounds__(64) void lossv_kernel(
    const float* __restrict__ mdl, const int* __restrict__ lab,
    float* __restrict__ acc, int C)
{
  int row = blockIdx.x, lane = threadIdx.x;
  const float* x = mdl + (size_t)row * C;
  float mx = -3.0e38f;
  for (int c = lane; c < C; c += 64) mx = fmaxf(mx, x[c]);
  mx = wmax(mx);
  float s = 0.f;
  for (int c = lane; c < C; c += 64) s += expf(x[c] - mx);
  s = wsum(s);
  if (lane == 0) atomicAdd(acc, logf(s) + mx - x[lab[row]]);
}

__global__ __launch_bounds__(256) void finalize_kernel(
    const float* __restrict__ sumexp, const float* __restrict__ diagmax,
    const float* __restrict__ rowsum, const float* __restrict__ colsum,
    const float* __restrict__ Ldiag, const float* __restrict__ lossv,
    float* __restrict__ out, int NB)
{
  int tid = threadIdx.x;
  float p = 0.f;
  for (int r = tid; r < 3 * NB; r += 256) p += logf(sumexp[r]) + TSCALE - diagmax[r];
  p *= (0.3f / (3.0f * NB));
  float q = 0.f;
  for (int i2 = tid; i2 < NB; i2 += 256)
    q += (logf(rowsum[i2]) + TSCALE - Ldiag[i2]) + (logf(colsum[i2]) + TSCALE - Ldiag[i2]);
  p += q * (0.25f / NB);
  __shared__ float red[256];
  red[tid] = p; __syncthreads();
  for (int s = 128; s > 0; s >>= 1){ if (tid < s) red[tid] += red[tid + s]; __syncthreads(); }
  if (tid == 0) out[0] = red[0] + 0.2f * (lossv[0] / NB);
}

extern "C" void kernel_launch(void* const* d_in, const int* in_sizes, int n_in,
                              void* d_out, int out_size, void* d_ws, size_t ws_size,
                              hipStream_t stream) {
  const float* obj = (const float*)d_in[0];
  const float* txt = (const float*)d_in[1];
  const float* mdl = (const float*)d_in[2];
  const int*   lab = (const int*)d_in[3];

  const int NB = in_sizes[1] / (4 * DD);   // B*5 = 1280
  const int C  = in_sizes[2] / NB;          // 504

  float* ws = (float*)d_ws;
  size_t o = 0;
  float* objn = ws + o; o += (size_t)NB * 8 * DD;
  float* argn = ws + o; o += (size_t)NB * 3 * DD;
  float* t1n  = ws + o; o += (size_t)NB * DD;
  float* ten  = ws + o; o += (size_t)NB * DD;
  float* ven  = ws + o; o += (size_t)NB * DD;
  float* diagmax = ws + o; o += (size_t)3 * NB;
  int*   diagidx = (int*)(ws + o); o += (size_t)3 * NB;
  float* Ldiag = ws + o; o += (size_t)NB;
  float* zr = ws + o;                      // zero-init region
  float* sumexp = zr;                      // 3*NB
  float* rowsum = zr + 3 * NB;             // NB
  float* colsum = rowsum + NB;             // NB
  float* lossv  = colsum + NB;             // 1

  hipMemsetAsync(zr, 0, (size_t)(5 * NB + 1) * sizeof(float), stream);

  norm_rows<<<NB * 12, 64, 0, stream>>>(obj, txt, objn, argn, t1n, NB);
  diag_kernel<<<3 * NB, 64, 0, stream>>>(argn, objn, diagmax, diagidx);
  wpg_gemm<<<dim3(NB * 8 / 128, NB * 3 / 128), 256, 0, stream>>>(argn, objn, sumexp);
  teve_kernel<<<NB, 64, 0, stream>>>(argn, objn, t1n, diagmax, diagidx, ten, ven);
  ec_gemm<<<dim3(NB / 128, NB / 128), 256, 0, stream>>>(ten, ven, rowsum, colsum, Ldiag);
  lossv_kernel<<<NB, 64, 0, stream>>>(mdl, lab, lossv, C);
  finalize_kernel<<<1, 256, 0, stream>>>(sumexp, diagmax, rowsum, colsum, Ldiag, lossv,
                                         (float*)d_out, NB);
}

// Round 2
// 230.806 us; speedup vs baseline: 3.8694x; 3.8694x over previous
//
#include <hip/hip_runtime.h>
#include <hip/hip_bf16.h>
#include <cstdint>
#include <cstddef>

#define DD 768
#define TSCALE 20.0f

typedef short bf16x8 __attribute__((ext_vector_type(8)));
typedef float f32x4 __attribute__((ext_vector_type(4)));

__device__ inline float wsum(float v){
  #pragma unroll
  for (int m = 1; m < 64; m <<= 1) v += __shfl_xor(v, m, 64);
  return v;
}
__device__ inline float wmax(float v){
  #pragma unroll
  for (int m = 1; m < 64; m <<= 1) v = fmaxf(v, __shfl_xor(v, m, 64));
  return v;
}

__device__ inline void gload_lds16(const void* g, void* l){
  __builtin_amdgcn_global_load_lds(
      (const __attribute__((address_space(1))) uint32_t*)g,
      (__attribute__((address_space(3))) uint32_t*)l, 16, 0, 0);
}

// Normalize rows: obj (8*NB), arg slots {0,2,3} (3*NB), text slot 1 (NB).
// Writes fp32 (for exact decision path) and bf16 (for MFMA GEMMs).
__global__ __launch_bounds__(64) void norm_rows(
    const float* __restrict__ obj, const float* __restrict__ txt,
    float* __restrict__ objn, float* __restrict__ argn, float* __restrict__ t1n,
    __hip_bfloat16* __restrict__ objb, __hip_bfloat16* __restrict__ argb, int NB)
{
  int row = blockIdx.x, lane = threadIdx.x;
  int NO = NB * 8, NA = NB * 3;
  const float* src; float* dst; __hip_bfloat16* bdst = nullptr;
  if (row < NO) {
    src = obj + (size_t)row * DD; dst = objn + (size_t)row * DD; bdst = objb + (size_t)row * DD;
  } else if (row < NO + NA) {
    int r = row - NO; int i = r / 3, j = r - i * 3; int s = (j == 0) ? 0 : (j + 1);
    src = txt + ((size_t)i * 4 + s) * DD; dst = argn + (size_t)r * DD; bdst = argb + (size_t)r * DD;
  } else {
    int i = row - NO - NA;
    src = txt + ((size_t)i * 4 + 1) * DD; dst = t1n + (size_t)i * DD;
  }
  float v[12]; float ss = 0.f;
  #pragma unroll
  for (int q = 0; q < 12; ++q){ v[q] = src[lane + q * 64]; ss += v[q] * v[q]; }
  ss = wsum(ss);
  float inv = 1.0f / fmaxf(sqrtf(ss), 1e-12f);
  #pragma unroll
  for (int q = 0; q < 12; ++q){
    float x = v[q] * inv;
    dst[lane + q * 64] = x;
    if (bdst) bdst[lane + q * 64] = __float2bfloat16(x);
  }
}

// Exact fp32 diagonal path: per (i,j) arg row, dots with own 8 objects.
__global__ __launch_bounds__(64) void diag_kernel(
    const float* __restrict__ argn, const float* __restrict__ objn,
    float* __restrict__ diagmax, int* __restrict__ diagidx)
{
  int r = blockIdx.x, lane = threadIdx.x;
  int i = r / 3;
  float a[12];
  #pragma unroll
  for (int q = 0; q < 12; ++q) a[q] = argn[(size_t)r * DD + lane + q * 64];
  float best = -3.0e38f; int bi = 0;
  for (int k = 0; k < 8; ++k){
    const float* o = objn + (size_t)(i * 8 + k) * DD;
    float s = 0.f;
    #pragma unroll
    for (int q = 0; q < 12; ++q) s += a[q] * o[lane + q * 64];
    s = wsum(s);
    if (s > best){ best = s; bi = k; }
  }
  if (lane == 0){ diagmax[r] = best * TSCALE; diagidx[r] = bi; }
}

// ---- bf16 MFMA GEMM, m97 structure: 128x128 tile, BK=32, 4 waves 2x2 ----
// wpg: A=argb [M=3*NB,768], B=objb [N=8*NB,768]; fused row sum(exp(20*c-20)).
__global__ __launch_bounds__(256) void wpg_gemm_mfma(
    const __hip_bfloat16* __restrict__ A, const __hip_bfloat16* __restrict__ B,
    float* __restrict__ sumexp)
{
  __shared__ __hip_bfloat16 As[128 * 32];
  __shared__ __hip_bfloat16 Bs[128 * 32];
  int tid = threadIdx.x;
  int bx = blockIdx.x, by = blockIdx.y;
  int wid = tid >> 6, lane = tid & 63;
  int wr = wid >> 1, wc = wid & 1;

  f32x4 acc[4][4];
  #pragma unroll
  for (int i = 0; i < 4; ++i)
    #pragma unroll
    for (int j = 0; j < 4; ++j) acc[i][j] = (f32x4){0.f, 0.f, 0.f, 0.f};

  const char* Ab = (const char*)(A + (size_t)(by * 128) * DD);
  const char* Bb = (const char*)(B + (size_t)(bx * 128) * DD);
  int srow = tid >> 2;              // 0..63 (4 threads per 64B row-chunk)
  int scol = (tid & 3) * 16;        // byte within 64B K-chunk
  char* AsB = (char*)As; char* BsB = (char*)Bs;
  int r = lane & 15, kg = (lane >> 4) * 8;

  for (int kb = 0; kb < DD * 2; kb += 64){
    gload_lds16(Ab + (size_t)srow * (DD*2) + kb + scol, AsB + tid * 16);
    gload_lds16(Ab + (size_t)(srow + 64) * (DD*2) + kb + scol, AsB + 4096 + tid * 16);
    gload_lds16(Bb + (size_t)srow * (DD*2) + kb + scol, BsB + tid * 16);
    gload_lds16(Bb + (size_t)(srow + 64) * (DD*2) + kb + scol, BsB + 4096 + tid * 16);
    __syncthreads();
    bf16x8 af[4], bfr[4];
    #pragma unroll
    for (int mi = 0; mi < 4; ++mi)
      af[mi] = *(const bf16x8*)&As[(wr * 64 + mi * 16 + r) * 32 + kg];
    #pragma unroll
    for (int ni = 0; ni < 4; ++ni)
      bfr[ni] = *(const bf16x8*)&Bs[(wc * 64 + ni * 16 + r) * 32 + kg];
    #pragma unroll
    for (int mi = 0; mi < 4; ++mi)
      #pragma unroll
      for (int ni = 0; ni < 4; ++ni)
        acc[mi][ni] = __builtin_amdgcn_mfma_f32_16x16x32_bf16(af[mi], bfr[ni], acc[mi][ni], 0, 0, 0);
    __syncthreads();
  }
  // epilogue: per-row sum of exp(20*c - 20); C layout col=lane&15, row=(lane>>4)*4+reg
  int rowbase = by * 128 + wr * 64 + ((lane >> 4) << 2);
  #pragma unroll
  for (int mi = 0; mi < 4; ++mi){
    #pragma unroll
    for (int rr = 0; rr < 4; ++rr){
      float s = 0.f;
      #pragma unroll
      for (int ni = 0; ni < 4; ++ni) s += expf(fmaf(acc[mi][ni][rr], TSCALE, -TSCALE));
      s += __shfl_xor(s, 1, 64); s += __shfl_xor(s, 2, 64);
      s += __shfl_xor(s, 4, 64); s += __shfl_xor(s, 8, 64);
      if ((lane & 15) == 0) atomicAdd(&sumexp[rowbase + mi * 16 + rr], s);
    }
  }
}

// ec: A=tenb, B=venb [NB,768]; fused row/col exp-sums + exact diag capture.
__global__ __launch_bounds__(256) void ec_gemm_mfma(
    const __hip_bfloat16* __restrict__ A, const __hip_bfloat16* __restrict__ B,
    float* __restrict__ rowsum, float* __restrict__ colsum, float* __restrict__ Ldiag)
{
  __shared__ __hip_bfloat16 As[128 * 32];
  __shared__ __hip_bfloat16 Bs[128 * 32];
  int tid = threadIdx.x;
  int bx = blockIdx.x, by = blockIdx.y;
  int wid = tid >> 6, lane = tid & 63;
  int wr = wid >> 1, wc = wid & 1;

  f32x4 acc[4][4];
  #pragma unroll
  for (int i = 0; i < 4; ++i)
    #pragma unroll
    for (int j = 0; j < 4; ++j) acc[i][j] = (f32x4){0.f, 0.f, 0.f, 0.f};

  const char* Ab = (const char*)(A + (size_t)(by * 128) * DD);
  const char* Bb = (const char*)(B + (size_t)(bx * 128) * DD);
  int srow = tid >> 2;
  int scol = (tid & 3) * 16;
  char* AsB = (char*)As; char* BsB = (char*)Bs;
  int r = lane & 15, kg = (lane >> 4) * 8;

  for (int kb = 0; kb < DD * 2; kb += 64){
    gload_lds16(Ab + (size_t)srow * (DD*2) + kb + scol, AsB + tid * 16);
    gload_lds16(Ab + (size_t)(srow + 64) * (DD*2) + kb + scol, AsB + 4096 + tid * 16);
    gload_lds16(Bb + (size_t)srow * (DD*2) + kb + scol, BsB + tid * 16);
    gload_lds16(Bb + (size_t)(srow + 64) * (DD*2) + kb + scol, BsB + 4096 + tid * 16);
    __syncthreads();
    bf16x8 af[4], bfr[4];
    #pragma unroll
    for (int mi = 0; mi < 4; ++mi)
      af[mi] = *(const bf16x8*)&As[(wr * 64 + mi * 16 + r) * 32 + kg];
    #pragma unroll
    for (int ni = 0; ni < 4; ++ni)
      bfr[ni] = *(const bf16x8*)&Bs[(wc * 64 + ni * 16 + r) * 32 + kg];
    #pragma unroll
    for (int mi = 0; mi < 4; ++mi)
      #pragma unroll
      for (int ni = 0; ni < 4; ++ni)
        acc[mi][ni] = __builtin_amdgcn_mfma_f32_16x16x32_bf16(af[mi], bfr[ni], acc[mi][ni], 0, 0, 0);
    __syncthreads();
  }
  int rowbase = by * 128 + wr * 64 + ((lane >> 4) << 2);
  float colacc[4] = {0.f, 0.f, 0.f, 0.f};
  #pragma unroll
  for (int mi = 0; mi < 4; ++mi){
    #pragma unroll
    for (int rr = 0; rr < 4; ++rr){
      float s = 0.f;
      #pragma unroll
      for (int ni = 0; ni < 4; ++ni){
        float e = expf(fmaf(acc[mi][ni][rr], TSCALE, -TSCALE));
        s += e; colacc[ni] += e;
      }
      s += __shfl_xor(s, 1, 64); s += __shfl_xor(s, 2, 64);
      s += __shfl_xor(s, 4, 64); s += __shfl_xor(s, 8, 64);
      if ((lane & 15) == 0) atomicAdd(&rowsum[rowbase + mi * 16 + rr], s);
    }
  }
  #pragma unroll
  for (int ni = 0; ni < 4; ++ni){
    float c = colacc[ni];
    c += __shfl_xor(c, 16, 64); c += __shfl_xor(c, 32, 64);
    if (lane < 16) atomicAdd(&colsum[bx * 128 + wc * 64 + ni * 16 + lane], c);
  }
  if (bx == by){
    #pragma unroll
    for (int mi = 0; mi < 4; ++mi)
      #pragma unroll
      for (int ni = 0; ni < 4; ++ni)
        #pragma unroll
        for (int rr = 0; rr < 4; ++rr){
          int grow = wr * 64 + mi * 16 + ((lane >> 4) << 2) + rr;
          int gcol = wc * 64 + ni * 16 + (lane & 15);
          if (grow == gcol) Ldiag[by * 128 + grow] = acc[mi][ni][rr] * TSCALE;
        }
  }
}

// te/ve assembly (fp32 decisions) -> bf16 outputs for ec GEMM
__global__ __launch_bounds__(64) void teve_kernel(
    const float* __restrict__ argn, const float* __restrict__ objn, const float* __restrict__ t1n,
    const float* __restrict__ diagmax, const int* __restrict__ diagidx,
    __hip_bfloat16* __restrict__ tenb, __hip_bfloat16* __restrict__ venb)
{
  int i = blockIdx.x, lane = threadIdx.x;
  float te[12], ve[12];
  #pragma unroll
  for (int q = 0; q < 12; ++q){ te[q] = t1n[(size_t)i * DD + lane + q * 64]; ve[q] = 0.f; }
  for (int j = 0; j < 3; ++j){
    int rr = i * 3 + j;
    if (diagmax[rr] > 1.0f){
      int k = diagidx[rr];
      const float* ap = argn + (size_t)rr * DD;
      const float* op = objn + (size_t)(i * 8 + k) * DD;
      #pragma unroll
      for (int q = 0; q < 12; ++q){ te[q] += ap[lane + q * 64]; ve[q] += op[lane + q * 64]; }
    }
  }
  float ss = 0.f;
  #pragma unroll
  for (int q = 0; q < 12; ++q) ss += te[q] * te[q];
  ss = wsum(ss);
  float inv = 1.0f / fmaxf(sqrtf(ss), 1e-12f);
  #pragma unroll
  for (int q = 0; q < 12; ++q) tenb[(size_t)i * DD + lane + q * 64] = __float2bfloat16(te[q] * inv);
  ss = 0.f;
  #pragma unroll
  for (int q = 0; q < 12; ++q) ss += ve[q] * ve[q];
  ss = wsum(ss);
  inv = 1.0f / fmaxf(sqrtf(ss), 1e-12f);
  #pragma unroll
  for (int q = 0; q < 12; ++q) venb[(size_t)i * DD + lane + q * 64] = __float2bfloat16(ve[q] * inv);
}

__global__ __launch_bounds__(64) void lossv_kernel(
    const float* __restrict__ mdl, const int* __restrict__ lab,
    float* __restrict__ acc, int C)
{
  int row = blockIdx.x, lane = threadIdx.x;
  const float* x = mdl + (size_t)row * C;
  float mx = -3.0e38f;
  for (int c = lane; c < C; c += 64) mx = fmaxf(mx, x[c]);
  mx = wmax(mx);
  float s = 0.f;
  for (int c = lane; c < C; c += 64) s += expf(x[c] - mx);
  s = wsum(s);
  if (lane == 0) atomicAdd(acc, logf(s) + mx - x[lab[row]]);
}

__global__ __launch_bounds__(256) void finalize_kernel(
    const float* __restrict__ sumexp, const float* __restrict__ diagmax,
    const float* __restrict__ rowsum, const float* __restrict__ colsum,
    const float* __restrict__ Ldiag, const float* __restrict__ lossv,
    float* __restrict__ out, int NB)
{
  int tid = threadIdx.x;
  float p = 0.f;
  for (int r = tid; r < 3 * NB; r += 256) p += logf(sumexp[r]) + TSCALE - diagmax[r];
  p *= (0.3f / (3.0f * NB));
  float q = 0.f;
  for (int i2 = tid; i2 < NB; i2 += 256)
    q += (logf(rowsum[i2]) + TSCALE - Ldiag[i2]) + (logf(colsum[i2]) + TSCALE - Ldiag[i2]);
  p += q * (0.25f / NB);
  __shared__ float red[256];
  red[tid] = p; __syncthreads();
  for (int s = 128; s > 0; s >>= 1){ if (tid < s) red[tid] += red[tid + s]; __syncthreads(); }
  if (tid == 0) out[0] = red[0] + 0.2f * (lossv[0] / NB);
}

extern "C" void kernel_launch(void* const* d_in, const int* in_sizes, int n_in,
                              void* d_out, int out_size, void* d_ws, size_t ws_size,
                              hipStream_t stream) {
  const float* obj = (const float*)d_in[0];
  const float* txt = (const float*)d_in[1];
  const float* mdl = (const float*)d_in[2];
  const int*   lab = (const int*)d_in[3];

  const int NB = in_sizes[1] / (4 * DD);   // 1280
  const int C  = in_sizes[2] / NB;          // 504

  float* ws = (float*)d_ws;
  size_t o = 0;
  float* objn = ws + o; o += (size_t)NB * 8 * DD;
  float* argn = ws + o; o += (size_t)NB * 3 * DD;
  float* t1n  = ws + o; o += (size_t)NB * DD;
  __hip_bfloat16* objb = (__hip_bfloat16*)(ws + o); o += (size_t)NB * 4 * DD;  // 8*NB*DD bf16
  __hip_bfloat16* argb = (__hip_bfloat16*)(ws + o); o += ((size_t)NB * 3 * DD + 1) / 2;
  __hip_bfloat16* tenb = (__hip_bfloat16*)(ws + o); o += (size_t)NB * DD / 2;
  __hip_bfloat16* venb = (__hip_bfloat16*)(ws + o); o += (size_t)NB * DD / 2;
  float* diagmax = ws + o; o += (size_t)3 * NB;
  int*   diagidx = (int*)(ws + o); o += (size_t)3 * NB;
  float* Ldiag = ws + o; o += (size_t)NB;
  float* zr = ws + o;                      // zero-init region
  float* sumexp = zr;                      // 3*NB
  float* rowsum = zr + 3 * NB;             // NB
  float* colsum = rowsum + NB;             // NB
  float* lossv  = colsum + NB;             // 1

  hipMemsetAsync(zr, 0, (size_t)(5 * NB + 1) * sizeof(float), stream);

  norm_rows<<<NB * 12, 64, 0, stream>>>(obj, txt, objn, argn, t1n, objb, argb, NB);
  diag_kernel<<<3 * NB, 64, 0, stream>>>(argn, objn, diagmax, diagidx);
  wpg_gemm_mfma<<<dim3(NB * 8 / 128, NB * 3 / 128), 256, 0, stream>>>(argb, objb, sumexp);
  teve_kernel<<<NB, 64, 0, stream>>>(argn, objn, t1n, diagmax, diagidx, tenb, venb);
  ec_gemm_mfma<<<dim3(NB / 128, NB / 128), 256, 0, stream>>>(tenb, venb, rowsum, colsum, Ldiag);
  lossv_kernel<<<NB, 64, 0, stream>>>(mdl, lab, lossv, C);
  finalize_kernel<<<1, 256, 0, stream>>>(sumexp, diagmax, rowsum, colsum, Ldiag, lossv,
                                         (float*)d_out, NB);
}